// Round 6
// baseline (90.115 us; speedup 1.0000x reference)
//
#include <hip/hip_runtime.h>

#define HH 512
#define WW 1024
#define HWSZ (HH*WW)
#define NCLS 19
#define KEEP 128
#define CTHR 0.1f
#define NBLK 512            // nms blocks = (WW/64)*(HH/16)

// ---------------- NMS (7x7, SAME) -> transposed per-block survivor segments ----------------
// keys layout: keys[slot*NBLK + block]  (so select's scans are lane-coalesced)
__global__ void nms_kernel(const float* __restrict__ hm_in, float* __restrict__ hm_out,
                           unsigned long long* __restrict__ keys, int* __restrict__ blkcnt,
                           int maxpb)
{
    const int TX = 64, TY = 16;
    __shared__ float sin_[TY + 6][TX + 6];
    __shared__ float shm[TY + 6][TX];
    __shared__ unsigned long long lkeys[TX * TY];
    __shared__ int lcnt;

    if (threadIdx.x == 0) lcnt = 0;

    int bx = blockIdx.x % (WW / TX);
    int by = blockIdx.x / (WW / TX);
    int ox = bx * TX, oy = by * TY;

    for (int i = threadIdx.x; i < (TY + 6) * (TX + 6); i += blockDim.x) {
        int ly = i / (TX + 6), lx = i % (TX + 6);
        int gy = oy + ly - 3, gx = ox + lx - 3;
        float v = 0.f;
        if (gy >= 0 && gy < HH && gx >= 0 && gx < WW) {
            float t = hm_in[gy * WW + gx];
            v = (t > CTHR) ? t : 0.f;
        }
        sin_[ly][lx] = v;
    }
    __syncthreads();

    for (int i = threadIdx.x; i < (TY + 6) * TX; i += blockDim.x) {
        int ly = i / TX, lx = i % TX;
        float m = sin_[ly][lx];
#pragma unroll
        for (int d = 1; d < 7; d++) m = fmaxf(m, sin_[ly][lx + d]);
        shm[ly][lx] = m;
    }
    __syncthreads();

    for (int i = threadIdx.x; i < TY * TX; i += blockDim.x) {
        int ly = i / TX, lx = i % TX;
        float m = shm[ly][lx];
#pragma unroll
        for (int d = 1; d < 7; d++) m = fmaxf(m, shm[ly + d][lx]);
        float c = sin_[ly + 3][lx + 3];
        float o = (m == c) ? c : 0.f;
        int gy = oy + ly, gx = ox + lx;
        hm_out[gy * WW + gx] = o;
        if (o > 0.f) {
            int pos = atomicAdd(&lcnt, 1);      // LDS atomic only
            unsigned int bits = __float_as_uint(o);
            unsigned int idx = (unsigned int)(gy * WW + gx);
            lkeys[pos] = ((unsigned long long)bits << 32) |
                         (unsigned long long)(0xFFFFFFFFu - idx);
        }
    }
    __syncthreads();
    int n = lcnt < maxpb ? lcnt : maxpb;
    if (threadIdx.x == 0) blkcnt[blockIdx.x] = n;   // unconditional: no init needed
    for (int i = threadIdx.x; i < n; i += blockDim.x)
        keys[(size_t)i * NBLK + blockIdx.x] = lkeys[i];
}

// ---------------- top-128: segmented scans, wave-aggregated hist, bitonic ---------------
__global__ void __launch_bounds__(256) select_kernel(const unsigned long long* __restrict__ keys,
                                                     const int* __restrict__ blkcnt, int maxpb,
                                                     float4* __restrict__ centers)
{
    __shared__ int scnt[NBLK];
    __shared__ unsigned int hist[2048 * 4];   // pass2: x4 replicated by tid&3; pass1 uses [b*4]
    __shared__ unsigned int seg[64];
    __shared__ int wred[8];
    __shared__ int s_bin, s_above, s_n;
    __shared__ unsigned long long buf[2048];

    int tid = threadIdx.x;
    int lane = tid & 63, wid = tid >> 6;
    int rep = tid & 3;
    unsigned long long lmask_lt = (1ull << lane) - 1ull;

    // counts, total, max
    int c0 = blkcnt[2 * tid], c1 = blkcnt[2 * tid + 1];
    c0 = c0 < 0 ? 0 : (c0 > maxpb ? maxpb : c0);
    c1 = c1 < 0 ? 0 : (c1 > maxpb ? maxpb : c1);
    scnt[2 * tid] = c0; scnt[2 * tid + 1] = c1;
    int s = c0 + c1, mx = c0 > c1 ? c0 : c1;
    for (int d = 32; d; d >>= 1) {
        s += __shfl_xor(s, d);
        int o = __shfl_xor(mx, d); mx = mx > o ? mx : o;
    }
    if (lane == 0) { wred[wid] = s; wred[4 + wid] = mx; }
    for (int i = tid; i < 2048 * 4; i += 256) hist[i] = 0;
    if (tid == 0) s_n = 0;
    __syncthreads();
    int cnt = wred[0] + wred[1] + wred[2] + wred[3];
    int m4 = wred[4] > wred[5] ? wred[4] : wred[5];
    int m5 = wred[6] > wred[7] ? wred[6] : wred[7];
    int maxc = m4 > m5 ? m4 : m5;
    int K = cnt < KEEP ? cnt : KEEP;
    int nslots = maxc * NBLK;

    // ---- scan 1: hist over top 11 key bits, WAVE-AGGREGATED adds (hot-bin degenerate data)
    for (int base = 0; base < nslots; base += 1024) {
        int bin[4];
#pragma unroll
        for (int u = 0; u < 4; u++) {
            int i = base + u * 256 + tid;
            int sg = i & (NBLK - 1), sl = i >> 9;
            bool pv = (i < nslots) && (sl < scnt[sg]);
            unsigned long long kv = pv ? keys[(size_t)sl * NBLK + sg] : 0ull;
            bin[u] = pv ? (int)(kv >> 53) : -1;
        }
#pragma unroll
        for (int u = 0; u < 4; u++) {
            unsigned long long remaining = __ballot(bin[u] >= 0);
            while (remaining) {
                int leader = __builtin_ctzll(remaining);
                int lb = __shfl(bin[u], leader);
                unsigned long long matches = __ballot(bin[u] == lb) & remaining;
                if (lane == leader) atomicAdd(&hist[lb * 4], (unsigned)__popcll(matches));
                remaining &= ~matches;
            }
        }
    }
    __syncthreads();
    if (tid < 64) {
        unsigned ssum = 0;
        for (int i = 0; i < 32; i++) {
            int b = tid * 32 + i;
            unsigned m = hist[b * 4] + hist[b * 4 + 1] + hist[b * 4 + 2] + hist[b * 4 + 3];
            hist[b * 4] = m; ssum += m;
        }
        seg[tid] = ssum;
    }
    __syncthreads();
    if (tid == 0) {
        int acc = 0, B = 0;
        if (K > 0) {
            for (int sgi = 63; sgi >= 0; sgi--) {
                if (acc + (int)seg[sgi] >= K) {
                    for (int b = sgi * 32 + 31;; b--) {
                        if (acc + (int)hist[b * 4] >= K) { B = b; break; }
                        acc += hist[b * 4];
                    }
                    break;
                }
                acc += seg[sgi];
            }
        }
        s_bin = B; s_above = acc;
    }
    __syncthreads();
    int B1 = s_bin, above1 = s_above;
    int K2 = K - above1;
    __syncthreads();
    for (int i = tid; i < 2048 * 4; i += 256) hist[i] = 0;
    __syncthreads();

    // ---- scan 2: hist over bits [52:42] within bin B1 (spread bins -> direct x4 atomics)
    for (int base = 0; base < nslots; base += 1024) {
        unsigned long long kv[4]; bool pv[4];
#pragma unroll
        for (int u = 0; u < 4; u++) {
            int i = base + u * 256 + tid;
            int sg = i & (NBLK - 1), sl = i >> 9;
            pv[u] = (i < nslots) && (sl < scnt[sg]);
            kv[u] = pv[u] ? keys[(size_t)sl * NBLK + sg] : 0ull;
        }
#pragma unroll
        for (int u = 0; u < 4; u++)
            if (pv[u] && (unsigned)(kv[u] >> 53) == (unsigned)B1)
                atomicAdd(&hist[((unsigned)((kv[u] >> 42) & 2047u)) * 4 + rep], 1u);
    }
    __syncthreads();
    if (tid < 64) {
        unsigned ssum = 0;
        for (int i = 0; i < 32; i++) {
            int b = tid * 32 + i;
            unsigned m = hist[b * 4] + hist[b * 4 + 1] + hist[b * 4 + 2] + hist[b * 4 + 3];
            hist[b * 4] = m; ssum += m;
        }
        seg[tid] = ssum;
    }
    __syncthreads();
    if (tid == 0) {
        int acc = 0, B = 0;
        if (K2 > 0) {
            for (int sgi = 63; sgi >= 0; sgi--) {
                if (acc + (int)seg[sgi] >= K2) {
                    for (int b = sgi * 32 + 31;; b--) {
                        if (acc + (int)hist[b * 4] >= K2) { B = b; break; }
                        acc += hist[b * 4];
                    }
                    break;
                }
                acc += seg[sgi];
            }
        }
        s_bin = B;
    }
    __syncthreads();
    unsigned long long cutPrefix = (((unsigned long long)B1 << 11) | (unsigned long long)s_bin);

    // ---- scan 3: collect keys with prefix >= cutoff, wave-aggregated push
    for (int base = 0; base < nslots; base += 1024) {
#pragma unroll
        for (int u = 0; u < 4; u++) {
            int i = base + u * 256 + tid;
            int sg = i & (NBLK - 1), sl = i >> 9;
            bool pv = (i < nslots) && (sl < scnt[sg]);
            unsigned long long kv = pv ? keys[(size_t)sl * NBLK + sg] : 0ull;
            bool want = pv && (kv >> 42) >= cutPrefix;
            unsigned long long mask = __ballot(want);
            if (mask) {
                int leader = __builtin_ctzll(mask);
                int bpos = 0;
                if (lane == leader) bpos = atomicAdd(&s_n, (int)__popcll(mask));
                bpos = __shfl(bpos, leader);
                if (want) {
                    int pos = bpos + (int)__popcll(mask & lmask_lt);
                    if (pos < 2048) buf[pos] = kv;
                }
            }
        }
    }
    __syncthreads();
    int n = s_n; if (n > 2048) n = 2048;
    int m = 256;                       // next pow2 >= n, min 256 (>= 2*KEEP)
    while (m < n) m <<= 1;
    for (int i = tid; i < m; i += 256) if (i >= n) buf[i] = 0ull;
    __syncthreads();

    // ---- bitonic sort descending over m elements (4-wave barriers)
    for (int kk = 2; kk <= m; kk <<= 1) {
        for (int j = kk >> 1; j > 0; j >>= 1) {
            for (int i = tid; i < m; i += 256) {
                int ixj = i ^ j;
                if (ixj > i) {
                    bool desc = ((i & kk) == 0);
                    unsigned long long a = buf[i], b = buf[ixj];
                    if ((a < b) == desc) { buf[i] = b; buf[ixj] = a; }
                }
            }
            __syncthreads();
        }
    }

    if (tid < KEEP) {
        unsigned long long k64 = buf[tid];
        float sc, cy, cx, a;
        if (k64 == 0ull) {
            sc = 0.f; cy = 0.f; cx = 0.f; a = 0.f;
        } else {
            sc = __uint_as_float((unsigned int)(k64 >> 32));
            unsigned int idx = 0xFFFFFFFFu - (unsigned int)(k64 & 0xFFFFFFFFu);
            cy = (float)(idx / WW);
            cx = (float)(idx % WW);
            a = cy * cy + cx * cx;                    // exact (< 2^24)
        }
        centers[tid] = make_float4(cy, cx, a, sc);
    }
}

// ---------------- fused argmax + thing mask + PRUNED nearest-center assignment ----------------
__global__ void __launch_bounds__(256) assign_kernel(
        const float* __restrict__ logits, const float* __restrict__ offs,
        const int* __restrict__ thing_ids, int n_thing,
        const float4* __restrict__ centers, float* __restrict__ out)
{
    __shared__ float4 sc[KEEP];
    __shared__ float4 skept[KEEP];
    __shared__ int   skidx[KEEP];
    __shared__ float slog[256 * NCLS];
    __shared__ float sred[16];
    __shared__ float ured[4];
    __shared__ int   wcnt[4];
    __shared__ int   s_nkept;
    __shared__ int   sids[32];

    int tid = threadIdx.x;
    if (tid < KEEP) sc[tid] = centers[tid];
    if (tid < n_thing) sids[tid] = thing_ids[tid];

    int bx = blockIdx.x & 63;
    int by = blockIdx.x >> 6;
    int lr = tid >> 4, lc = tid & 15;
    int gy = by * 16 + lr, gx = bx * 16 + lc;
    int p  = gy * WW + gx;

    // stage logits tile via float4: 16 rows x 76 float4 (tile base 16B-aligned: 304%4==0)
    {
        const float4* src4 = (const float4*)(logits + ((size_t)(by * 16) * WW + bx * 16) * NCLS);
        float4* dst4 = (float4*)slog;
        const int R4 = (WW * NCLS) / 4;   // 4864
        for (int i = tid; i < 16 * 76; i += 256) {
            int r = i / 76, c = i % 76;
            dst4[i] = src4[(size_t)r * R4 + c];
        }
    }

    float2 off2 = ((const float2*)offs)[p];
    float py = __fadd_rn((float)gy, off2.x);
    float px = __fadd_rn((float)gx, off2.y);

    // block-wide bounding box of (py,px)
    float ymn = py, ymx = py, xmn = px, xmx = px;
    for (int d = 32; d; d >>= 1) {
        ymn = fminf(ymn, __shfl_xor(ymn, d));
        ymx = fmaxf(ymx, __shfl_xor(ymx, d));
        xmn = fminf(xmn, __shfl_xor(xmn, d));
        xmx = fmaxf(xmx, __shfl_xor(xmx, d));
    }
    if ((tid & 63) == 0) {
        int w = tid >> 6;
        sred[w * 4 + 0] = ymn; sred[w * 4 + 1] = ymx;
        sred[w * 4 + 2] = xmn; sred[w * 4 + 3] = xmx;
    }
    __syncthreads();   // slog, sred, sc, sids ready

    ymn = fminf(fminf(sred[0], sred[4]), fminf(sred[8],  sred[12]));
    ymx = fmaxf(fmaxf(sred[1], sred[5]), fmaxf(sred[9],  sred[13]));
    xmn = fminf(fminf(sred[2], sred[6]), fminf(sred[10], sred[14]));
    xmx = fmaxf(fmaxf(sred[3], sred[7]), fmaxf(sred[11], sred[15]));

    // per-center conservative bounds (threads 0..127)
    float L = INFINITY, U = INFINITY;
    bool valid = false;
    if (tid < KEEP) {
        float4 c4 = sc[tid];
        valid = (c4.w > 0.f);
        if (valid) {
            float dyl = fmaxf(fmaxf(ymn - c4.x, c4.x - ymx), 0.f);
            float dxl = fmaxf(fmaxf(xmn - c4.y, c4.y - xmx), 0.f);
            L = dyl * dyl + dxl * dxl;
            float dyu = fmaxf(fabsf(c4.x - ymn), fabsf(c4.x - ymx));
            float dxu = fmaxf(fabsf(c4.y - xmn), fabsf(c4.y - xmx));
            U = dyu * dyu + dxu * dxu;
        }
    }
    float u = U;
    for (int d = 32; d; d >>= 1) u = fminf(u, __shfl_xor(u, d));
    if ((tid & 63) == 0) ured[tid >> 6] = u;
    __syncthreads();
    float Umin = fminf(fminf(ured[0], ured[1]), fminf(ured[2], ured[3]));

    // keep flags + order-preserving compaction (margin 8 >> rounding slop ~2)
    bool keep = valid && (L <= Umin + 8.0f);
    unsigned long long mask = __ballot(keep);
    int lane = tid & 63;
    int prefix = __popcll(mask & ((1ull << lane) - 1ull));
    if (lane == 0) wcnt[tid >> 6] = __popcll(mask);
    __syncthreads();
    int base = (tid >> 6) == 1 ? wcnt[0] : 0;
    if (keep) { skept[base + prefix] = sc[tid]; skidx[base + prefix] = tid; }
    if (tid == 0) s_nkept = wcnt[0] + wcnt[1];
    __syncthreads();

    // semantic argmax (first-wins); stride-19 LDS (odd stride -> 2-way max, free)
    const float* l = slog + tid * NCLS;
    float best = l[0];
    int cls = 0;
#pragma unroll
    for (int c = 1; c < NCLS; c++) {
        float v = l[c];
        if (v > best) { best = v; cls = c; }
    }
    bool thing = false;
    for (int j = 0; j < n_thing; j++) thing = thing || (cls == sids[j]);

    float b = __fadd_rn(__fmul_rn(py, py), __fmul_rn(px, px));

    float bestd = INFINITY;
    int bi = -1;
    int nk = s_nkept;
    for (int k = 0; k < nk; k++) {
        float4 c4 = skept[k];
        // replicate f32 gemm: m = fma(cx,px, rn(cy*py)); d2 = rn(rn(a-2m)+b)
        float m  = __fmaf_rn(c4.y, px, __fmul_rn(c4.x, py));
        float d2 = __fadd_rn(__fsub_rn(c4.z, __fadd_rn(m, m)), b);
        if (d2 < bestd) { bestd = d2; bi = k; }
    }

    float inst, smap;
    if (bi < 0) { inst = thing ? 1.f : 0.f; smap = 0.f; }
    else {
        inst = thing ? (float)(skidx[bi] + 1) : 0.f;
        smap = thing ? skept[bi].w : 0.f;
    }
    out[p] = inst;
    out[2 * HWSZ + p] = smap;
    out[3 * HWSZ + p] = (float)cls;
}

extern "C" void kernel_launch(void* const* d_in, const int* in_sizes, int n_in,
                              void* d_out, int out_size, void* d_ws, size_t ws_size,
                              hipStream_t stream) {
    const float* logits = (const float*)d_in[0];
    const float* heat   = (const float*)d_in[1];
    const float* offs   = (const float*)d_in[2];
    const int*   tids   = (const int*)d_in[3];
    int n_thing = in_sizes[3];
    if (n_thing > 32) n_thing = 32;

    float* out = (float*)d_out;
    char* ws = (char*)d_ws;
    // layout: blkcnt[512] @0 (2KB) | centers @4096 (2KB) | keys @16384 (transposed [maxpb][512])
    int* blkcnt = (int*)ws;
    float4* centers = (float4*)(ws + 4096);
    long long avail = (long long)ws_size - 16384;
    int maxpb = (int)(avail / (NBLK * 8));
    if (maxpb > 120) maxpb = 120;    // 120 slots/block >> expected ~30 max survivors/tile
    if (maxpb < 16) maxpb = 16;
    unsigned long long* keys = (unsigned long long*)(ws + 16384);

    nms_kernel<<<dim3(NBLK), dim3(256), 0, stream>>>(heat, out + HWSZ, keys, blkcnt, maxpb);
    select_kernel<<<dim3(1), dim3(256), 0, stream>>>(keys, blkcnt, maxpb, centers);
    assign_kernel<<<dim3((WW / 16) * (HH / 16)), dim3(256), 0, stream>>>(logits, offs, tids, n_thing, centers, out);
}

// Round 7
// 78.186 us; speedup vs baseline: 1.1526x; 1.1526x over previous
//
#include <hip/hip_runtime.h>

#define HH 512
#define WW 1024
#define HWSZ (HH*WW)
#define NCLS 19
#define KEEP 128
#define CTHR 0.1f
#define NBLK 512            // nms blocks = (WW/64)*(HH/16)
#define NRED 16             // reduce blocks
#define SEGPB (NBLK / NRED) // 32 segments per reduce block

// ---------------- NMS (7x7, SAME) -> transposed per-block survivor segments ----------------
__global__ void nms_kernel(const float* __restrict__ hm_in, float* __restrict__ hm_out,
                           unsigned long long* __restrict__ keys, int* __restrict__ blkcnt,
                           int maxpb)
{
    const int TX = 64, TY = 16;
    __shared__ float sin_[TY + 6][TX + 6];
    __shared__ float shm[TY + 6][TX];
    __shared__ unsigned long long lkeys[TX * TY];
    __shared__ int lcnt;

    if (threadIdx.x == 0) lcnt = 0;

    int bx = blockIdx.x % (WW / TX);
    int by = blockIdx.x / (WW / TX);
    int ox = bx * TX, oy = by * TY;

    for (int i = threadIdx.x; i < (TY + 6) * (TX + 6); i += blockDim.x) {
        int ly = i / (TX + 6), lx = i % (TX + 6);
        int gy = oy + ly - 3, gx = ox + lx - 3;
        float v = 0.f;
        if (gy >= 0 && gy < HH && gx >= 0 && gx < WW) {
            float t = hm_in[gy * WW + gx];
            v = (t > CTHR) ? t : 0.f;
        }
        sin_[ly][lx] = v;
    }
    __syncthreads();

    for (int i = threadIdx.x; i < (TY + 6) * TX; i += blockDim.x) {
        int ly = i / TX, lx = i % TX;
        float m = sin_[ly][lx];
#pragma unroll
        for (int d = 1; d < 7; d++) m = fmaxf(m, sin_[ly][lx + d]);
        shm[ly][lx] = m;
    }
    __syncthreads();

    for (int i = threadIdx.x; i < TY * TX; i += blockDim.x) {
        int ly = i / TX, lx = i % TX;
        float m = shm[ly][lx];
#pragma unroll
        for (int d = 1; d < 7; d++) m = fmaxf(m, shm[ly + d][lx]);
        float c = sin_[ly + 3][lx + 3];
        float o = (m == c) ? c : 0.f;
        int gy = oy + ly, gx = ox + lx;
        hm_out[gy * WW + gx] = o;
        if (o > 0.f) {
            int pos = atomicAdd(&lcnt, 1);      // LDS atomic only
            unsigned int bits = __float_as_uint(o);
            unsigned int idx = (unsigned int)(gy * WW + gx);
            lkeys[pos] = ((unsigned long long)bits << 32) |
                         (unsigned long long)(0xFFFFFFFFu - idx);
        }
    }
    __syncthreads();
    int n = lcnt < maxpb ? lcnt : maxpb;
    if (threadIdx.x == 0) blkcnt[blockIdx.x] = n;   // unconditional: no init needed
    for (int i = threadIdx.x; i < n; i += blockDim.x)
        keys[(size_t)i * NBLK + blockIdx.x] = lkeys[i];
}

// ---------------- stage A: 16 blocks, each -> sorted local top-128 of its 32 segments -------
__global__ void __launch_bounds__(256) reduce_kernel(const unsigned long long* __restrict__ keys,
                                                     const int* __restrict__ blkcnt, int maxpb,
                                                     unsigned long long* __restrict__ gtop)
{
    __shared__ unsigned long long buf[2048];
    __shared__ int scnt[SEGPB];
    __shared__ int s_n;

    int tid = threadIdx.x, lane = tid & 63;
    unsigned long long lmask_lt = (1ull << lane) - 1ull;
    int g0 = blockIdx.x * SEGPB;

    if (tid < SEGPB) {
        int c = blkcnt[g0 + tid];
        scnt[tid] = c < 0 ? 0 : (c > maxpb ? maxpb : c);
    }
    if (tid == 0) s_n = 0;
    __syncthreads();
    int mx = 0;
    for (int j = 0; j < SEGPB; j++) { int c = scnt[j]; mx = c > mx ? c : mx; }  // broadcast reads
    int total = SEGPB * mx;

    int base = 0;
    do {
        int wend = base + 1792 < total ? base + 1792 : total;   // window: 7*256 slots
        for (int ii = 0; ii < 7; ii++) {                        // uniform trip count (safe ballots)
            int i = base + ii * 256 + tid;
            int sg = i & (SEGPB - 1), sl = i / SEGPB;
            bool pv = (i < wend) && (sl < scnt[sg]);
            unsigned long long kv = pv ? keys[(size_t)sl * NBLK + (g0 + sg)] : 0ull;
            unsigned long long mask = __ballot(pv);
            if (mask) {
                int leader = __builtin_ctzll(mask);
                int bpos = 0;
                if (lane == leader) bpos = atomicAdd(&s_n, (int)__popcll(mask));
                bpos = __shfl(bpos, leader);
                if (pv) buf[bpos + (int)__popcll(mask & lmask_lt)] = kv;
            }
        }
        __syncthreads();
        int n = s_n;                      // <= 128 + 1792 <= 2048 by construction
        int m = 256; while (m < n) m <<= 1;
        for (int i = tid; i < m; i += 256) if (i >= n) buf[i] = 0ull;
        __syncthreads();
        for (int kk = 2; kk <= m; kk <<= 1) {
            for (int j = kk >> 1; j > 0; j >>= 1) {
                for (int i = tid; i < m; i += 256) {
                    int ixj = i ^ j;
                    if (ixj > i) {
                        bool desc = ((i & kk) == 0);
                        unsigned long long a = buf[i], b = buf[ixj];
                        if ((a < b) == desc) { buf[i] = b; buf[ixj] = a; }
                    }
                }
                __syncthreads();
            }
        }
        if (tid == 0) s_n = n < KEEP ? n : KEEP;   // keep top-128, next window appends after
        base += 1792;
        __syncthreads();
    } while (base < total);

    if (tid < KEEP) gtop[blockIdx.x * KEEP + tid] = buf[tid];   // zero-padded by sort
}

// ---------------- stage B: all-LDS radix narrow + sort of the 2048 semifinalists ------------
__global__ void __launch_bounds__(256) select_kernel(const unsigned long long* __restrict__ gtop,
                                                     float4* __restrict__ centers)
{
    __shared__ unsigned long long buf[2048];
    __shared__ unsigned long long buf2[2048];
    __shared__ unsigned int hist[2048 * 2];   // x2 replicated
    __shared__ unsigned int seg[64];
    __shared__ int s_bin, s_above, s_n, s_nz;

    int tid = threadIdx.x;
    int lane = tid & 63, wid = tid >> 6;
    int rep = wid & 1;
    unsigned long long lmask_lt = (1ull << lane) - 1ull;

    if (tid == 0) { s_n = 0; s_nz = 0; }
    for (int i = tid; i < 2048 * 2; i += 256) hist[i] = 0;
    __syncthreads();

    // load + count nonzero (wave-aggregated)
    int mynz = 0;
    for (int i = tid; i < 2048; i += 256) {
        unsigned long long kv = gtop[i];
        buf[i] = kv;
        mynz += (kv != 0ull);
    }
    for (int d = 32; d; d >>= 1) mynz += __shfl_xor(mynz, d);
    if (lane == 0) atomicAdd(&s_nz, mynz);
    __syncthreads();
    int cnt_nz = s_nz;
    int K = cnt_nz < KEEP ? cnt_nz : KEEP;

    // ---- pass 1: hist over top 11 bits, wave-aggregated (hot-bin data)
    for (int ii = 0; ii < 8; ii++) {
        int i = ii * 256 + tid;
        int bin = (int)(buf[i] >> 53);
        unsigned long long remaining = __ballot(true) & ~0ull;
        remaining = 0xFFFFFFFFFFFFFFFFull;
        while (remaining) {
            int leader = __builtin_ctzll(remaining);
            int lb = __shfl(bin, leader);
            unsigned long long matches = __ballot(bin == lb) & remaining;
            if (lane == leader) atomicAdd(&hist[lb * 2 + rep], (unsigned)__popcll(matches));
            remaining &= ~matches;
        }
    }
    __syncthreads();
    if (tid < 64) {
        unsigned ssum = 0;
        for (int i = 0; i < 32; i++) {
            int b = tid * 32 + i;
            unsigned m = hist[b * 2] + hist[b * 2 + 1];
            hist[b * 2] = m; ssum += m;
        }
        seg[tid] = ssum;
    }
    __syncthreads();
    if (tid == 0) {
        int acc = 0, B = 0;
        if (K > 0) {
            for (int sgi = 63; sgi >= 0; sgi--) {
                if (acc + (int)seg[sgi] >= K) {
                    for (int b = sgi * 32 + 31;; b--) {
                        if (acc + (int)hist[b * 2] >= K) { B = b; break; }
                        acc += hist[b * 2];
                    }
                    break;
                }
                acc += seg[sgi];
            }
        }
        s_bin = B; s_above = acc;
    }
    __syncthreads();
    int B1 = s_bin, above1 = s_above;
    int K2 = K - above1;
    __syncthreads();
    for (int i = tid; i < 2048 * 2; i += 256) hist[i] = 0;
    __syncthreads();

    // ---- pass 2: hist over bits [52:42] within bin B1 (spread -> direct x2 atomics)
    for (int ii = 0; ii < 8; ii++) {
        unsigned long long kv = buf[ii * 256 + tid];
        if ((unsigned)(kv >> 53) == (unsigned)B1)
            atomicAdd(&hist[((unsigned)((kv >> 42) & 2047u)) * 2 + rep], 1u);
    }
    __syncthreads();
    if (tid < 64) {
        unsigned ssum = 0;
        for (int i = 0; i < 32; i++) {
            int b = tid * 32 + i;
            unsigned m = hist[b * 2] + hist[b * 2 + 1];
            hist[b * 2] = m; ssum += m;
        }
        seg[tid] = ssum;
    }
    __syncthreads();
    if (tid == 0) {
        int acc = 0, B = 0;
        if (K2 > 0) {
            for (int sgi = 63; sgi >= 0; sgi--) {
                if (acc + (int)seg[sgi] >= K2) {
                    for (int b = sgi * 32 + 31;; b--) {
                        if (acc + (int)hist[b * 2] >= K2) { B = b; break; }
                        acc += hist[b * 2];
                    }
                    break;
                }
                acc += seg[sgi];
            }
        }
        s_bin = B;
    }
    __syncthreads();
    unsigned long long cutPrefix = (((unsigned long long)B1 << 11) | (unsigned long long)s_bin);

    // ---- collect keys with prefix >= cutoff (wave-aggregated push into buf2)
    for (int ii = 0; ii < 8; ii++) {
        unsigned long long kv = buf[ii * 256 + tid];
        bool want = (kv >> 42) >= cutPrefix && kv != 0ull;
        unsigned long long mask = __ballot(want);
        if (mask) {
            int leader = __builtin_ctzll(mask);
            int bpos = 0;
            if (lane == leader) bpos = atomicAdd(&s_n, (int)__popcll(mask));
            bpos = __shfl(bpos, leader);
            if (want) buf2[bpos + (int)__popcll(mask & lmask_lt)] = kv;
        }
    }
    __syncthreads();
    int n = s_n;                        // <= 2048
    int m = 256; while (m < n) m <<= 1;
    for (int i = tid; i < m; i += 256) if (i >= n) buf2[i] = 0ull;
    __syncthreads();

    for (int kk = 2; kk <= m; kk <<= 1) {
        for (int j = kk >> 1; j > 0; j >>= 1) {
            for (int i = tid; i < m; i += 256) {
                int ixj = i ^ j;
                if (ixj > i) {
                    bool desc = ((i & kk) == 0);
                    unsigned long long a = buf2[i], b = buf2[ixj];
                    if ((a < b) == desc) { buf2[i] = b; buf2[ixj] = a; }
                }
            }
            __syncthreads();
        }
    }

    if (tid < KEEP) {
        unsigned long long k64 = buf2[tid];
        float sc, cy, cx, a;
        if (k64 == 0ull) {
            sc = 0.f; cy = 0.f; cx = 0.f; a = 0.f;
        } else {
            sc = __uint_as_float((unsigned int)(k64 >> 32));
            unsigned int idx = 0xFFFFFFFFu - (unsigned int)(k64 & 0xFFFFFFFFu);
            cy = (float)(idx / WW);
            cx = (float)(idx % WW);
            a = cy * cy + cx * cx;                    // exact (< 2^24)
        }
        centers[tid] = make_float4(cy, cx, a, sc);
    }
}

// ---------------- fused argmax + thing mask + PRUNED nearest-center assignment ----------------
__global__ void __launch_bounds__(256) assign_kernel(
        const float* __restrict__ logits, const float* __restrict__ offs,
        const int* __restrict__ thing_ids, int n_thing,
        const float4* __restrict__ centers, float* __restrict__ out)
{
    __shared__ float4 sc[KEEP];
    __shared__ float4 skept[KEEP];
    __shared__ int   skidx[KEEP];
    __shared__ float slog[256 * NCLS];
    __shared__ float sred[16];
    __shared__ float ured[4];
    __shared__ int   wcnt[4];
    __shared__ int   s_nkept;
    __shared__ int   sids[32];

    int tid = threadIdx.x;
    if (tid < KEEP) sc[tid] = centers[tid];
    if (tid < n_thing) sids[tid] = thing_ids[tid];

    int bx = blockIdx.x & 63;
    int by = blockIdx.x >> 6;
    int lr = tid >> 4, lc = tid & 15;
    int gy = by * 16 + lr, gx = bx * 16 + lc;
    int p  = gy * WW + gx;

    // stage logits tile via float4: 16 rows x 76 float4 (tile base 16B-aligned: 304%4==0)
    {
        const float4* src4 = (const float4*)(logits + ((size_t)(by * 16) * WW + bx * 16) * NCLS);
        float4* dst4 = (float4*)slog;
        const int R4 = (WW * NCLS) / 4;   // 4864
        for (int i = tid; i < 16 * 76; i += 256) {
            int r = i / 76, c = i % 76;
            dst4[i] = src4[(size_t)r * R4 + c];
        }
    }

    float2 off2 = ((const float2*)offs)[p];
    float py = __fadd_rn((float)gy, off2.x);
    float px = __fadd_rn((float)gx, off2.y);

    // block-wide bounding box of (py,px)
    float ymn = py, ymx = py, xmn = px, xmx = px;
    for (int d = 32; d; d >>= 1) {
        ymn = fminf(ymn, __shfl_xor(ymn, d));
        ymx = fmaxf(ymx, __shfl_xor(ymx, d));
        xmn = fminf(xmn, __shfl_xor(xmn, d));
        xmx = fmaxf(xmx, __shfl_xor(xmx, d));
    }
    if ((tid & 63) == 0) {
        int w = tid >> 6;
        sred[w * 4 + 0] = ymn; sred[w * 4 + 1] = ymx;
        sred[w * 4 + 2] = xmn; sred[w * 4 + 3] = xmx;
    }
    __syncthreads();   // slog, sred, sc, sids ready

    ymn = fminf(fminf(sred[0], sred[4]), fminf(sred[8],  sred[12]));
    ymx = fmaxf(fmaxf(sred[1], sred[5]), fmaxf(sred[9],  sred[13]));
    xmn = fminf(fminf(sred[2], sred[6]), fminf(sred[10], sred[14]));
    xmx = fmaxf(fmaxf(sred[3], sred[7]), fmaxf(sred[11], sred[15]));

    // per-center conservative bounds (threads 0..127)
    float L = INFINITY, U = INFINITY;
    bool valid = false;
    if (tid < KEEP) {
        float4 c4 = sc[tid];
        valid = (c4.w > 0.f);
        if (valid) {
            float dyl = fmaxf(fmaxf(ymn - c4.x, c4.x - ymx), 0.f);
            float dxl = fmaxf(fmaxf(xmn - c4.y, c4.y - xmx), 0.f);
            L = dyl * dyl + dxl * dxl;
            float dyu = fmaxf(fabsf(c4.x - ymn), fabsf(c4.x - ymx));
            float dxu = fmaxf(fabsf(c4.y - xmn), fabsf(c4.y - xmx));
            U = dyu * dyu + dxu * dxu;
        }
    }
    float u = U;
    for (int d = 32; d; d >>= 1) u = fminf(u, __shfl_xor(u, d));
    if ((tid & 63) == 0) ured[tid >> 6] = u;
    __syncthreads();
    float Umin = fminf(fminf(ured[0], ured[1]), fminf(ured[2], ured[3]));

    // keep flags + order-preserving compaction (margin 8 >> rounding slop ~2)
    bool keep = valid && (L <= Umin + 8.0f);
    unsigned long long mask = __ballot(keep);
    int lane = tid & 63;
    int prefix = __popcll(mask & ((1ull << lane) - 1ull));
    if (lane == 0) wcnt[tid >> 6] = __popcll(mask);
    __syncthreads();
    int base = (tid >> 6) == 1 ? wcnt[0] : 0;
    if (keep) { skept[base + prefix] = sc[tid]; skidx[base + prefix] = tid; }
    if (tid == 0) s_nkept = wcnt[0] + wcnt[1];
    __syncthreads();

    // semantic argmax (first-wins); stride-19 LDS (odd stride -> 2-way max, free)
    const float* l = slog + tid * NCLS;
    float best = l[0];
    int cls = 0;
#pragma unroll
    for (int c = 1; c < NCLS; c++) {
        float v = l[c];
        if (v > best) { best = v; cls = c; }
    }
    bool thing = false;
    for (int j = 0; j < n_thing; j++) thing = thing || (cls == sids[j]);

    float b = __fadd_rn(__fmul_rn(py, py), __fmul_rn(px, px));

    float bestd = INFINITY;
    int bi = -1;
    int nk = s_nkept;
    for (int k = 0; k < nk; k++) {
        float4 c4 = skept[k];
        // replicate f32 gemm: m = fma(cx,px, rn(cy*py)); d2 = rn(rn(a-2m)+b)
        float m  = __fmaf_rn(c4.y, px, __fmul_rn(c4.x, py));
        float d2 = __fadd_rn(__fsub_rn(c4.z, __fadd_rn(m, m)), b);
        if (d2 < bestd) { bestd = d2; bi = k; }
    }

    float inst, smap;
    if (bi < 0) { inst = thing ? 1.f : 0.f; smap = 0.f; }
    else {
        inst = thing ? (float)(skidx[bi] + 1) : 0.f;
        smap = thing ? skept[bi].w : 0.f;
    }
    out[p] = inst;
    out[2 * HWSZ + p] = smap;
    out[3 * HWSZ + p] = (float)cls;
}

extern "C" void kernel_launch(void* const* d_in, const int* in_sizes, int n_in,
                              void* d_out, int out_size, void* d_ws, size_t ws_size,
                              hipStream_t stream) {
    const float* logits = (const float*)d_in[0];
    const float* heat   = (const float*)d_in[1];
    const float* offs   = (const float*)d_in[2];
    const int*   tids   = (const int*)d_in[3];
    int n_thing = in_sizes[3];
    if (n_thing > 32) n_thing = 32;

    float* out = (float*)d_out;
    char* ws = (char*)d_ws;
    // layout: blkcnt[512] @0 | centers @4096 | gtop @8192 (16KB) | keys @32768 ([maxpb][512])
    int* blkcnt = (int*)ws;
    float4* centers = (float4*)(ws + 4096);
    unsigned long long* gtop = (unsigned long long*)(ws + 8192);
    long long avail = (long long)ws_size - 32768;
    int maxpb = (int)(avail / (NBLK * 8));
    if (maxpb > 120) maxpb = 120;    // >> expected ~45 max survivors/tile
    if (maxpb < 16) maxpb = 16;
    unsigned long long* keys = (unsigned long long*)(ws + 32768);

    nms_kernel<<<dim3(NBLK), dim3(256), 0, stream>>>(heat, out + HWSZ, keys, blkcnt, maxpb);
    reduce_kernel<<<dim3(NRED), dim3(256), 0, stream>>>(keys, blkcnt, maxpb, gtop);
    select_kernel<<<dim3(1), dim3(256), 0, stream>>>(gtop, centers);
    assign_kernel<<<dim3((WW / 16) * (HH / 16)), dim3(256), 0, stream>>>(logits, offs, tids, n_thing, centers, out);
}